// Round 4
// baseline (90.900 us; speedup 1.0000x reference)
//
#include <hip/hip_runtime.h>
#include <hip/hip_bf16.h>
#include <math.h>

#define DIM 256
#define BB 1024
#define KK 128
#define PITCH 264   // bf16 elements per LDS row: 528 B, 16B-aligned rows

typedef __attribute__((ext_vector_type(8))) short short8;
typedef __attribute__((ext_vector_type(4))) float float4v;

__device__ __forceinline__ float dot4(const float4 a, const float4 b) {
    return a.x*b.x + a.y*b.y + a.z*b.z + a.w*b.w;
}

// two f32 -> packed bf16x2 bits (RNE); lowers to v_cvt_pk_bf16_f32
__device__ __forceinline__ unsigned bf2bits(float a, float b) {
    float2 t; t.x = a; t.y = b;
    __hip_bfloat162 h = __float22bfloat162_rn(t);
    unsigned u; __builtin_memcpy(&u, &h, 4);
    return u;
}

// One block per batch element. 512 threads = 8 waves. Exactly 4 waves/EU
// (2 blocks/CU, LDS-limited) -> give the allocator the full 128-VGPR budget.
__global__ __attribute__((amdgpu_flat_work_group_size(512, 512),
                          amdgpu_waves_per_eu(4, 4)))
void fused_main(
    const float* __restrict__ feature,
    const float* __restrict__ text,
    const float* __restrict__ virt,
    const float* __restrict__ gumbel,
    const int*   __restrict__ ego,
    const int*   __restrict__ adj,
    float*       __restrict__ score_raw)
{
    __shared__ unsigned short tbs[KK * PITCH];   // 67584 B
    __shared__ float fpart[8][DIM];              // 8192 B
    __shared__ float spart[8];

    const int b    = blockIdx.x;
    const int tid  = threadIdx.x;
    const int wave = tid >> 6;
    const int lane = tid & 63;
    const int g    = lane >> 4;   // 16-lane group id (0..3)
    const int c    = lane & 15;   // position within group

    // lane (g,c) owns cols {64m + 4c + i} (m=0..3, i=0..3)
    float4 vm[4];
    #pragma unroll
    for (int m = 0; m < 4; ++m) vm[m] = *(const float4*)(virt + 64*m + 4*c);

    float vv2 = 0.f;
    #pragma unroll
    for (int m = 0; m < 4; ++m) vv2 += dot4(vm[m], vm[m]);
    #pragma unroll
    for (int msk = 1; msk < 16; msk <<= 1) vv2 += __shfl_xor(vv2, msk);  // ||v||^2

    const int* ego_b = ego + b * KK;
    const int  base  = wave * 16;

    int eidx[4];
    #pragma unroll
    for (int it = 0; it < 4; ++it) eidx[it] = ego_b[base + it*4 + g];

    float4 fd[4];
    #pragma unroll
    for (int m = 0; m < 4; ++m) fd[m] = make_float4(0.f, 0.f, 0.f, 0.f);

    // ---- Phase A: 16 lanes per row, 4 rows/iter, depth-2 software pipeline.
    float4 snt[2][4], snf[2][4];
    #pragma unroll
    for (int p = 0; p < 2; ++p) {
        const float* tr = text    + (size_t)eidx[p] * DIM + 4*c;
        const float* fr = feature + (size_t)eidx[p] * DIM + 4*c;
        #pragma unroll
        for (int m = 0; m < 4; ++m) {
            snt[p][m] = *(const float4*)(tr + 64*m);
            snf[p][m] = *(const float4*)(fr + 64*m);
        }
    }

    #pragma unroll
    for (int it = 0; it < 4; ++it) {
        const int sl = it & 1;
        float4 ct[4], cf[4];
        #pragma unroll
        for (int m = 0; m < 4; ++m) { ct[m] = snt[sl][m]; cf[m] = snf[sl][m]; }
        if (it < 2) {
            const float* tr = text    + (size_t)eidx[it+2] * DIM + 4*c;
            const float* fr = feature + (size_t)eidx[it+2] * DIM + 4*c;
            #pragma unroll
            for (int m = 0; m < 4; ++m) {
                snt[sl][m] = *(const float4*)(tr + 64*m);
                snf[sl][m] = *(const float4*)(fr + 64*m);
            }
        }

        float st = 0.f, sf = 0.f, sv = 0.f;
        #pragma unroll
        for (int m = 0; m < 4; ++m) {
            st += dot4(ct[m], ct[m]);
            sf += dot4(cf[m], cf[m]);
            sv += dot4(ct[m], vm[m]);
        }
        #pragma unroll
        for (int msk = 1; msk < 16; msk <<= 1) {
            st += __shfl_xor(st, msk);
            sf += __shfl_xor(sf, msk);
            sv += __shfl_xor(sv, msk);
        }

        const float inv_ne = __builtin_amdgcn_rsqf(fmaxf(st, 1e-24f));
        const float inv_nf = __builtin_amdgcn_rsqf(fmaxf(sf, 1e-24f));
        // ||emb - v||^2 = 1 + ||v||^2 - 2 (t.v)/||t||
        const float nw2    = fmaxf(1.f + vv2 - 2.f * sv * inv_ne, 1e-24f);
        const float inv_nt = __builtin_amdgcn_rsqf(nw2);

        const int row = base + it*4 + g;
        unsigned short* dst = &tbs[row * PITCH + 4*c];
        #pragma unroll
        for (int m = 0; m < 4; ++m) {
            const float e0 = ct[m].x * inv_ne, e1 = ct[m].y * inv_ne;
            const float e2 = ct[m].z * inv_ne, e3 = ct[m].w * inv_ne;
            fd[m].x += cf[m].x * inv_nf - e0;
            fd[m].y += cf[m].y * inv_nf - e1;
            fd[m].z += cf[m].z * inv_nf - e2;
            fd[m].w += cf[m].w * inv_nf - e3;
            uint2 pk;
            pk.x = bf2bits((e0 - vm[m].x) * inv_nt, (e1 - vm[m].y) * inv_nt);
            pk.y = bf2bits((e2 - vm[m].z) * inv_nt, (e3 - vm[m].w) * inv_nt);
            *(uint2*)(dst + 64*m) = pk;
        }
    }

    // reduce f_diff partials across the 4 groups (rows of this wave)
    #pragma unroll
    for (int msk = 16; msk < 64; msk <<= 1) {
        #pragma unroll
        for (int m = 0; m < 4; ++m) {
            fd[m].x += __shfl_xor(fd[m].x, msk);
            fd[m].y += __shfl_xor(fd[m].y, msk);
            fd[m].z += __shfl_xor(fd[m].z, msk);
            fd[m].w += __shfl_xor(fd[m].w, msk);
        }
    }
    if (g == 0) {
        #pragma unroll
        for (int m = 0; m < 4; ++m)
            *(float4*)&fpart[wave][64*m + 4*c] = fd[m];
    }

    // issue adj then gumbel loads pre-barrier: latency hides under the
    // barrier + MFMA loop. adj gets packed to a 32-bit mask early in phase B.
    const float* gb = gumbel + (size_t)b * KK * KK;
    const int*   ab = adj    + (size_t)b * KK * KK;
    int atmp[32];
    #pragma unroll
    for (int r = 0; r < 4; ++r) {
        const int* ar = ab + (base + g*4 + r) * KK + c;
        #pragma unroll
        for (int t = 0; t < 8; ++t)
            atmp[r*8 + t] = __builtin_nontemporal_load(ar + t*16);
    }
    float gvv[32];
    #pragma unroll
    for (int r = 0; r < 4; ++r) {
        const float* gr = gb + (base + g*4 + r) * KK + c;
        #pragma unroll
        for (int t = 0; t < 8; ++t)
            gvv[r*8 + t] = __builtin_nontemporal_load(gr + t*16);
    }

    __syncthreads();

    // ---- Phase B: Gram matrix via MFMA (A-frag == B-frag loader, perm cancels)
    float4v acc[8];
    const float4v zero = {0.f, 0.f, 0.f, 0.f};
    #pragma unroll
    for (int t = 0; t < 8; ++t) acc[t] = zero;

    // first 2 K-steps, then retire atmp into a 1-VGPR mask, then the rest
    #pragma unroll
    for (int q = 0; q < 2; ++q) {
        const int dq = q * 32 + g * 8;
        const short8 afr = *(const short8*)&tbs[(base + c) * PITCH + dq];
        #pragma unroll
        for (int t = 0; t < 8; ++t) {
            const short8 bfr = *(const short8*)&tbs[(t*16 + c) * PITCH + dq];
            acc[t] = __builtin_amdgcn_mfma_f32_16x16x32_bf16(afr, bfr, acc[t], 0, 0, 0);
        }
    }
    unsigned am = 0;
    #pragma unroll
    for (int i = 0; i < 32; ++i) am |= (atmp[i] ? 1u : 0u) << i;
    #pragma unroll
    for (int q = 2; q < 8; ++q) {
        const int dq = q * 32 + g * 8;
        const short8 afr = *(const short8*)&tbs[(base + c) * PITCH + dq];
        #pragma unroll
        for (int t = 0; t < 8; ++t) {
            const short8 bfr = *(const short8*)&tbs[(t*16 + c) * PITCH + dq];
            acc[t] = __builtin_amdgcn_mfma_f32_16x16x32_bf16(afr, bfr, acc[t], 0, 0, 0);
        }
    }

    // ---- softmax rows + s_diff: one 4-step tree per row (no max needed:
    // |sim-0.5+gumbel| <~ 14 -> exp safe in fp32).
    // sum (adj-p)^2 = sum(adj) - invS*(2 sum(adj e) - invS sum(e^2)), p = e*invS
    float rs = 0.f;
    #pragma unroll
    for (int r = 0; r < 4; ++r) {
        const unsigned mr = (am >> (r*8)) & 0xffu;
        float s = 0.f, a2 = 0.f, a3 = 0.f;
        #pragma unroll
        for (int t = 0; t < 8; ++t) {
            const float vt = acc[t][r] - 0.5f + gvv[r*8 + t];
            const float et = __expf(vt);
            s  += et;
            a3 += et * et;
            a2 += ((mr >> t) & 1u) ? et : 0.f;
        }
        float fia = (float)__popc(mr);
        #pragma unroll
        for (int msk = 1; msk < 16; msk <<= 1) {
            s   += __shfl_xor(s,   msk);
            a2  += __shfl_xor(a2,  msk);
            a3  += __shfl_xor(a3,  msk);
            fia += __shfl_xor(fia, msk);
        }
        const float invS = __builtin_amdgcn_rcpf(s);
        const float T = fia - invS * (2.f * a2 - invS * a3);
        rs += sqrtf(fmaxf(T, 0.f));
    }
    rs += __shfl_xor(rs, 16);
    rs += __shfl_xor(rs, 32);          // 16-row strip total
    if (lane == 0) spart[wave] = rs;
    __syncthreads();

    if (wave == 0) {
        float d0 = 0.f, d1 = 0.f, d2 = 0.f, d3 = 0.f;
        #pragma unroll
        for (int w = 0; w < 8; ++w) {
            d0 += fpart[w][lane];
            d1 += fpart[w][lane + 64];
            d2 += fpart[w][lane + 128];
            d3 += fpart[w][lane + 192];
        }
        const float inv = 1.f / 128.f;
        d0 *= inv; d1 *= inv; d2 *= inv; d3 *= inv;
        float q2 = d0*d0 + d1*d1 + d2*d2 + d3*d3;
        #pragma unroll
        for (int m = 1; m < 64; m <<= 1) q2 += __shfl_xor(q2, m);
        if (lane == 0) {
            float stot = 0.f;
            #pragma unroll
            for (int w = 0; w < 8; ++w) stot += spart[w];
            score_raw[b] = stot * (1.f / 128.f) + sqrtf(q2);
        }
    }
}

__global__ __launch_bounds__(1024) void finalize(
    const float* __restrict__ score_raw,
    const int*   __restrict__ label,
    float*       __restrict__ out)
{
    __shared__ float wmin[16], wmax[16], wsum[16];
    const int tid = threadIdx.x;
    const float s = score_raw[tid];
    float mn = s, mx = s;
    #pragma unroll
    for (int m = 1; m < 64; m <<= 1) {
        mn = fminf(mn, __shfl_xor(mn, m));
        mx = fmaxf(mx, __shfl_xor(mx, m));
    }
    if ((tid & 63) == 0) { wmin[tid >> 6] = mn; wmax[tid >> 6] = mx; }
    __syncthreads();
    float gmn = wmin[0], gmx = wmax[0];
    #pragma unroll
    for (int w = 1; w < 16; ++w) {
        gmn = fminf(gmn, wmin[w]);
        gmx = fmaxf(gmx, wmax[w]);
    }
    const float score = (s - gmn) / (gmx - gmn);
    out[tid] = score;

    const float y  = (float)label[tid];
    const float sc = fminf(fmaxf(score, 1e-7f), 1.f - 1e-7f);
    float term = -(y * logf(sc) + (1.f - y) * log1pf(-sc));
    #pragma unroll
    for (int m = 1; m < 64; m <<= 1) term += __shfl_xor(term, m);
    if ((tid & 63) == 0) wsum[tid >> 6] = term;
    __syncthreads();
    if (tid == 0) {
        float tot = 0.f;
        #pragma unroll
        for (int w = 0; w < 16; ++w) tot += wsum[w];
        out[BB] = tot / (1024.f * 1024.f);
    }
}

extern "C" void kernel_launch(void* const* d_in, const int* in_sizes, int n_in,
                              void* d_out, int out_size, void* d_ws, size_t ws_size,
                              hipStream_t stream) {
    const float* feature = (const float*)d_in[0];
    const float* text    = (const float*)d_in[1];
    const float* virt    = (const float*)d_in[2];
    const float* gumbel  = (const float*)d_in[3];
    const int*   ego     = (const int*)d_in[4];
    const int*   adj     = (const int*)d_in[5];
    const int*   label   = (const int*)d_in[6];
    float* out       = (float*)d_out;
    float* score_raw = (float*)d_ws;

    fused_main<<<BB, 512, 0, stream>>>(feature, text, virt, gumbel, ego, adj, score_raw);
    finalize<<<1, 1024, 0, stream>>>(score_raw, label, out);
}

// Round 5
// 76.027 us; speedup vs baseline: 1.1956x; 1.1956x over previous
//
#include <hip/hip_runtime.h>
#include <hip/hip_bf16.h>
#include <math.h>

#define DIM 256
#define BB 1024
#define KK 128
#define PITCH 264   // bf16 elements per LDS row: 528 B, 16B-aligned rows

typedef __attribute__((ext_vector_type(8))) short short8;
typedef __attribute__((ext_vector_type(4))) float float4v;

__device__ __forceinline__ float dot4(const float4 a, const float4 b) {
    return a.x*b.x + a.y*b.y + a.z*b.z + a.w*b.w;
}

// two f32 -> packed bf16x2 bits (RNE); lowers to v_cvt_pk_bf16_f32
__device__ __forceinline__ unsigned bf2bits(float a, float b) {
    float2 t; t.x = a; t.y = b;
    __hip_bfloat162 h = __float22bfloat162_rn(t);
    unsigned u; __builtin_memcpy(&u, &h, 4);
    return u;
}

// One block per batch element. 1024 threads = 16 waves; 2 blocks/CU
// (LDS-limited) -> 32 waves/CU = 100% occupancy. Per-wave state sized for
// the 64-VGPR budget the allocator enforces at 8 waves/EU.
__global__ __launch_bounds__(1024, 8) void fused_main(
    const float* __restrict__ feature,
    const float* __restrict__ text,
    const float* __restrict__ virt,
    const float* __restrict__ gumbel,
    const int*   __restrict__ ego,
    const int*   __restrict__ adj,
    float*       __restrict__ score_raw)
{
    __shared__ unsigned short tbs[KK * PITCH];   // 67584 B
    __shared__ float fpart8[8][DIM];             // 8192 B  (pair-combined f_diff)
    __shared__ float rowpart[KK][8];             // 4096 B  ({s,a2,a3,fia} x 2 halves)
    __shared__ float spart[2];

    const int b    = blockIdx.x;
    const int tid  = threadIdx.x;
    const int wave = tid >> 6;        // 0..15
    const int lane = tid & 63;

    const int* ego_b = ego + b * KK;

    // ---- Phase A: wave handles rows wave*8 .. wave*8+7, full wave per row,
    //      lane owns dims 4*lane..4*lane+3, depth-2 load pipeline.
    const float4 vm = ((const float4*)virt)[lane];
    float vv2 = dot4(vm, vm);
    #pragma unroll
    for (int m = 1; m < 64; m <<= 1) vv2 += __shfl_xor(vv2, m);   // ||v||^2

    const int baseA = wave * 8;
    int eidx[8];
    #pragma unroll
    for (int k = 0; k < 8; ++k) eidx[k] = ego_b[baseA + k];

    float4 fdv = make_float4(0.f, 0.f, 0.f, 0.f);

    float4 pt[2], pf[2];
    #pragma unroll
    for (int p = 0; p < 2; ++p) {
        pt[p] = ((const float4*)(text    + (size_t)eidx[p] * DIM))[lane];
        pf[p] = ((const float4*)(feature + (size_t)eidx[p] * DIM))[lane];
    }

    #pragma unroll
    for (int k = 0; k < 8; ++k) {
        const int sl = k & 1;
        const float4 ct = pt[sl], cf = pf[sl];
        if (k < 6) {
            pt[sl] = ((const float4*)(text    + (size_t)eidx[k+2] * DIM))[lane];
            pf[sl] = ((const float4*)(feature + (size_t)eidx[k+2] * DIM))[lane];
        }

        float st = dot4(ct, ct), sf = dot4(cf, cf), sv = dot4(ct, vm);
        #pragma unroll
        for (int m = 1; m < 64; m <<= 1) {
            st += __shfl_xor(st, m);
            sf += __shfl_xor(sf, m);
            sv += __shfl_xor(sv, m);
        }

        const float inv_ne = __builtin_amdgcn_rsqf(fmaxf(st, 1e-24f));
        const float inv_nf = __builtin_amdgcn_rsqf(fmaxf(sf, 1e-24f));
        // ||emb - v||^2 = 1 + ||v||^2 - 2 (t.v)/||t||
        const float nw2    = fmaxf(1.f + vv2 - 2.f * sv * inv_ne, 1e-24f);
        const float inv_nt = __builtin_amdgcn_rsqf(nw2);

        const float e0 = ct.x * inv_ne, e1 = ct.y * inv_ne;
        const float e2 = ct.z * inv_ne, e3 = ct.w * inv_ne;
        fdv.x += cf.x * inv_nf - e0;
        fdv.y += cf.y * inv_nf - e1;
        fdv.z += cf.z * inv_nf - e2;
        fdv.w += cf.w * inv_nf - e3;

        uint2 pk;
        pk.x = bf2bits((e0 - vm.x) * inv_nt, (e1 - vm.y) * inv_nt);
        pk.y = bf2bits((e2 - vm.z) * inv_nt, (e3 - vm.w) * inv_nt);
        *(uint2*)&tbs[(baseA + k) * PITCH + 4 * lane] = pk;
    }

    // f_diff pair combine: odd waves park partials, even waves add after barrier
    if (wave & 1) *(float4*)&fpart8[wave >> 1][4 * lane] = fdv;

    __syncthreads();   // tbs complete; odd-wave fpart8 visible

    if (!(wave & 1)) {
        float4 o = *(float4*)&fpart8[wave >> 1][4 * lane];
        o.x += fdv.x; o.y += fdv.y; o.z += fdv.z; o.w += fdv.w;
        *(float4*)&fpart8[wave >> 1][4 * lane] = o;
    }

    // ---- Phase B: wave -> 16-row strip x 64-col half of the Gram matrix.
    const int strip = wave >> 1;      // 0..7
    const int half  = wave & 1;       // 0..1
    const int g     = lane >> 4;      // 0..3
    const int c     = lane & 15;
    const int baseR = strip * 16;

    // gumbel loads issued before the MFMA loop; latency hides under it
    const float* gb = gumbel + (size_t)b * KK * KK;
    float gvv[16];
    #pragma unroll
    for (int r = 0; r < 4; ++r) {
        const float* gr = gb + (baseR + g*4 + r) * KK + half*64 + c;
        #pragma unroll
        for (int t = 0; t < 4; ++t)
            gvv[r*4 + t] = __builtin_nontemporal_load(gr + t*16);
    }

    float4v acc[4];
    const float4v zero = {0.f, 0.f, 0.f, 0.f};
    #pragma unroll
    for (int t = 0; t < 4; ++t) acc[t] = zero;

    #pragma unroll
    for (int q = 0; q < 8; ++q) {
        const int dq = q * 32 + g * 8;
        const short8 afr = *(const short8*)&tbs[(baseR + c) * PITCH + dq];
        #pragma unroll
        for (int t = 0; t < 4; ++t) {
            const short8 bfr = *(const short8*)&tbs[(half*64 + t*16 + c) * PITCH + dq];
            acc[t] = __builtin_amdgcn_mfma_f32_16x16x32_bf16(afr, bfr, acc[t], 0, 0, 0);
        }
    }

    // adj -> 16-bit mask (loads issue together; one latency hit)
    const int* ab = adj + (size_t)b * KK * KK;
    unsigned am = 0;
    #pragma unroll
    for (int r = 0; r < 4; ++r) {
        const int* ar = ab + (baseR + g*4 + r) * KK + half*64 + c;
        #pragma unroll
        for (int t = 0; t < 4; ++t)
            am |= (__builtin_nontemporal_load(ar + t*16) ? 1u : 0u) << (r*4 + t);
    }

    // softmax partials per row (no max: |sim-0.5+gumbel| small, fp32-safe)
    #pragma unroll
    for (int r = 0; r < 4; ++r) {
        const unsigned mr = (am >> (r*4)) & 0xFu;
        float s = 0.f, a2 = 0.f, a3 = 0.f;
        #pragma unroll
        for (int t = 0; t < 4; ++t) {
            const float vt = acc[t][r] - 0.5f + gvv[r*4 + t];
            const float et = __expf(vt);
            s  += et;
            a3 += et * et;
            a2 += ((mr >> t) & 1u) ? et : 0.f;
        }
        float fia = (float)__popc(mr);
        #pragma unroll
        for (int msk = 1; msk < 16; msk <<= 1) {
            s   += __shfl_xor(s,   msk);
            a2  += __shfl_xor(a2,  msk);
            a3  += __shfl_xor(a3,  msk);
            fia += __shfl_xor(fia, msk);
        }
        if (c == 0) {
            float4 pk4; pk4.x = s; pk4.y = a2; pk4.z = a3; pk4.w = fia;
            *(float4*)&rowpart[baseR + g*4 + r][half * 4] = pk4;
        }
    }

    __syncthreads();   // rowpart complete; even-wave fpart8 write-back complete

    // combine halves: thread tid<128 owns one row
    if (tid < KK) {
        const float4 pa = *(const float4*)&rowpart[tid][0];
        const float4 pb = *(const float4*)&rowpart[tid][4];
        const float s   = pa.x + pb.x;
        const float a2  = pa.y + pb.y;
        const float a3  = pa.z + pb.z;
        const float fia = pa.w + pb.w;
        // sum (adj-p)^2 = sum(adj) - invS*(2 sum(adj e) - invS sum(e^2))
        const float invS = __builtin_amdgcn_rcpf(s);
        float sq = sqrtf(fmaxf(fia - invS * (2.f * a2 - invS * a3), 0.f));
        #pragma unroll
        for (int m = 1; m < 64; m <<= 1) sq += __shfl_xor(sq, m);
        if (lane == 0) spart[wave] = sq;   // wave 0 or 1
    }

    __syncthreads();

    if (wave == 0) {
        float4 d = make_float4(0.f, 0.f, 0.f, 0.f);
        #pragma unroll
        for (int j = 0; j < 8; ++j) {
            const float4 p = *(const float4*)&fpart8[j][4 * lane];
            d.x += p.x; d.y += p.y; d.z += p.z; d.w += p.w;
        }
        const float inv = 1.f / 128.f;
        d.x *= inv; d.y *= inv; d.z *= inv; d.w *= inv;
        float q2 = dot4(d, d);
        #pragma unroll
        for (int m = 1; m < 64; m <<= 1) q2 += __shfl_xor(q2, m);
        if (lane == 0)
            score_raw[b] = (spart[0] + spart[1]) * (1.f / 128.f) + sqrtf(q2);
    }
}

__global__ __launch_bounds__(1024) void finalize(
    const float* __restrict__ score_raw,
    const int*   __restrict__ label,
    float*       __restrict__ out)
{
    __shared__ float wmin[16], wmax[16], wsum[16];
    const int tid = threadIdx.x;
    const float s = score_raw[tid];
    float mn = s, mx = s;
    #pragma unroll
    for (int m = 1; m < 64; m <<= 1) {
        mn = fminf(mn, __shfl_xor(mn, m));
        mx = fmaxf(mx, __shfl_xor(mx, m));
    }
    if ((tid & 63) == 0) { wmin[tid >> 6] = mn; wmax[tid >> 6] = mx; }
    __syncthreads();
    float gmn = wmin[0], gmx = wmax[0];
    #pragma unroll
    for (int w = 1; w < 16; ++w) {
        gmn = fminf(gmn, wmin[w]);
        gmx = fmaxf(gmx, wmax[w]);
    }
    const float score = (s - gmn) / (gmx - gmn);
    out[tid] = score;

    const float y  = (float)label[tid];
    const float sc = fminf(fmaxf(score, 1e-7f), 1.f - 1e-7f);
    float term = -(y * logf(sc) + (1.f - y) * log1pf(-sc));
    #pragma unroll
    for (int m = 1; m < 64; m <<= 1) term += __shfl_xor(term, m);
    if ((tid & 63) == 0) wsum[tid >> 6] = term;
    __syncthreads();
    if (tid == 0) {
        float tot = 0.f;
        #pragma unroll
        for (int w = 0; w < 16; ++w) tot += wsum[w];
        out[BB] = tot / (1024.f * 1024.f);
    }
}

extern "C" void kernel_launch(void* const* d_in, const int* in_sizes, int n_in,
                              void* d_out, int out_size, void* d_ws, size_t ws_size,
                              hipStream_t stream) {
    const float* feature = (const float*)d_in[0];
    const float* text    = (const float*)d_in[1];
    const float* virt    = (const float*)d_in[2];
    const float* gumbel  = (const float*)d_in[3];
    const int*   ego     = (const int*)d_in[4];
    const int*   adj     = (const int*)d_in[5];
    const int*   label   = (const int*)d_in[6];
    float* out       = (float*)d_out;
    float* score_raw = (float*)d_ws;

    fused_main<<<BB, 1024, 0, stream>>>(feature, text, virt, gumbel, ego, adj, score_raw);
    finalize<<<1, 1024, 0, stream>>>(score_raw, label, out);
}

// Round 6
// 74.800 us; speedup vs baseline: 1.2153x; 1.0164x over previous
//
#include <hip/hip_runtime.h>
#include <hip/hip_bf16.h>
#include <math.h>

#define DIM 256
#define BB 1024
#define KK 128
#define PITCH 264   // bf16 elements per LDS row: 528 B, 16B-aligned rows

typedef __attribute__((ext_vector_type(8))) short short8;
typedef __attribute__((ext_vector_type(4))) float float4v;

__device__ __forceinline__ float dot4(const float4 a, const float4 b) {
    return a.x*b.x + a.y*b.y + a.z*b.z + a.w*b.w;
}

// two f32 -> packed bf16x2 bits (RNE); lowers to v_cvt_pk_bf16_f32
__device__ __forceinline__ unsigned bf2bits(float a, float b) {
    float2 t; t.x = a; t.y = b;
    __hip_bfloat162 h = __float22bfloat162_rn(t);
    unsigned u; __builtin_memcpy(&u, &h, 4);
    return u;
}

// One block per batch element. 1024 threads = 16 waves; LDS 80 KB -> exactly
// 2 blocks/CU = 8 waves/EU. Pin waves_per_eu to (8,8): VGPR budget is exactly
// 64 and the allocator has no incentive to under-allocate (R5 picked 32 and
// spilled 12 MB to scratch).
__global__ __attribute__((amdgpu_flat_work_group_size(1024, 1024),
                          amdgpu_waves_per_eu(8, 8)))
void fused_main(
    const float* __restrict__ feature,
    const float* __restrict__ text,
    const float* __restrict__ virt,
    const float* __restrict__ gumbel,
    const int*   __restrict__ ego,
    const int*   __restrict__ adj,
    float*       __restrict__ score_raw)
{
    __shared__ unsigned short tbs[KK * PITCH];   // 67584 B
    __shared__ float fpart8[8][DIM];             // 8192 B  (pair-combined f_diff)
    __shared__ float rowpart[KK][8];             // 4096 B  ({s,a2,a3,fia} x 2 halves)
    __shared__ float spart[2];

    const int b    = blockIdx.x;
    const int tid  = threadIdx.x;
    const int wave = tid >> 6;        // 0..15
    const int lane = tid & 63;

    const int* ego_b = ego + b * KK;

    // ---- Phase A: wave handles rows wave*8 .. wave*8+7, full wave per row,
    //      lane owns dims 4*lane..4*lane+3, depth-2 load pipeline.
    const float4 vm = ((const float4*)virt)[lane];
    float vv2 = dot4(vm, vm);
    #pragma unroll
    for (int m = 1; m < 64; m <<= 1) vv2 += __shfl_xor(vv2, m);   // ||v||^2

    const int baseA = wave * 8;
    int eidx[8];
    #pragma unroll
    for (int k = 0; k < 8; ++k) eidx[k] = ego_b[baseA + k];

    float4 fdv = make_float4(0.f, 0.f, 0.f, 0.f);

    float4 pt[2], pf[2];
    #pragma unroll
    for (int p = 0; p < 2; ++p) {
        pt[p] = ((const float4*)(text    + (size_t)eidx[p] * DIM))[lane];
        pf[p] = ((const float4*)(feature + (size_t)eidx[p] * DIM))[lane];
    }

    #pragma unroll
    for (int k = 0; k < 8; ++k) {
        const int sl = k & 1;
        const float4 ct = pt[sl], cf = pf[sl];
        if (k < 6) {
            pt[sl] = ((const float4*)(text    + (size_t)eidx[k+2] * DIM))[lane];
            pf[sl] = ((const float4*)(feature + (size_t)eidx[k+2] * DIM))[lane];
        }

        float st = dot4(ct, ct), sf = dot4(cf, cf), sv = dot4(ct, vm);
        #pragma unroll
        for (int m = 1; m < 64; m <<= 1) {
            st += __shfl_xor(st, m);
            sf += __shfl_xor(sf, m);
            sv += __shfl_xor(sv, m);
        }

        const float inv_ne = __builtin_amdgcn_rsqf(fmaxf(st, 1e-24f));
        const float inv_nf = __builtin_amdgcn_rsqf(fmaxf(sf, 1e-24f));
        // ||emb - v||^2 = 1 + ||v||^2 - 2 (t.v)/||t||
        const float nw2    = fmaxf(1.f + vv2 - 2.f * sv * inv_ne, 1e-24f);
        const float inv_nt = __builtin_amdgcn_rsqf(nw2);

        const float e0 = ct.x * inv_ne, e1 = ct.y * inv_ne;
        const float e2 = ct.z * inv_ne, e3 = ct.w * inv_ne;
        fdv.x += cf.x * inv_nf - e0;
        fdv.y += cf.y * inv_nf - e1;
        fdv.z += cf.z * inv_nf - e2;
        fdv.w += cf.w * inv_nf - e3;

        uint2 pk;
        pk.x = bf2bits((e0 - vm.x) * inv_nt, (e1 - vm.y) * inv_nt);
        pk.y = bf2bits((e2 - vm.z) * inv_nt, (e3 - vm.w) * inv_nt);
        *(uint2*)&tbs[(baseA + k) * PITCH + 4 * lane] = pk;
    }

    // f_diff pair combine: odd waves park partials, even waves add after barrier
    if (wave & 1) *(float4*)&fpart8[wave >> 1][4 * lane] = fdv;

    __syncthreads();   // tbs complete; odd-wave fpart8 visible

    if (!(wave & 1)) {
        float4 o = *(float4*)&fpart8[wave >> 1][4 * lane];
        o.x += fdv.x; o.y += fdv.y; o.z += fdv.z; o.w += fdv.w;
        *(float4*)&fpart8[wave >> 1][4 * lane] = o;
    }

    // ---- Phase B: wave -> 16-row strip x 64-col half of the Gram matrix.
    const int strip = wave >> 1;      // 0..7
    const int half  = wave & 1;       // 0..1
    const int g     = lane >> 4;      // 0..3
    const int c     = lane & 15;
    const int baseR = strip * 16;

    const float* gr = gumbel + ((size_t)b * KK + baseR + g*4) * KK + half*64 + c;
    const int*   ar = adj    + ((size_t)b * KK + baseR + g*4) * KK + half*64 + c;

    float4v acc[4];
    const float4v zero = {0.f, 0.f, 0.f, 0.f};
    #pragma unroll
    for (int t = 0; t < 4; ++t) acc[t] = zero;

    int   atmp[16];
    float gvv[16];

    // MFMA loop with adj (q0..q3) and gumbel (q4..q7) load-issue interleaved:
    // each row's loads get >=4 q-steps of MFMA/ds_read cover before use.
    #pragma unroll
    for (int q = 0; q < 8; ++q) {
        if (q < 4) {
            #pragma unroll
            for (int t = 0; t < 4; ++t)
                atmp[q*4 + t] = __builtin_nontemporal_load(ar + q*KK + t*16);
        } else {
            const int r = q - 4;
            #pragma unroll
            for (int t = 0; t < 4; ++t)
                gvv[r*4 + t] = __builtin_nontemporal_load(gr + r*KK + t*16);
        }
        const int dq = q * 32 + g * 8;
        const short8 afr = *(const short8*)&tbs[(baseR + c) * PITCH + dq];
        #pragma unroll
        for (int t = 0; t < 4; ++t) {
            const short8 bfr = *(const short8*)&tbs[(half*64 + t*16 + c) * PITCH + dq];
            acc[t] = __builtin_amdgcn_mfma_f32_16x16x32_bf16(afr, bfr, acc[t], 0, 0, 0);
        }
    }

    // softmax partials per row (no max: |sim-0.5+gumbel| <= ~14, fp32-safe)
    #pragma unroll
    for (int r = 0; r < 4; ++r) {
        float s = 0.f, a2 = 0.f, a3 = 0.f;
        int   ia = 0;
        #pragma unroll
        for (int t = 0; t < 4; ++t) {
            const float vt = acc[t][r] - 0.5f + gvv[r*4 + t];
            const float et = __expf(vt);
            const int   ad = atmp[r*4 + t];
            s  += et;
            a3 += et * et;
            a2 += ad ? et : 0.f;
            ia += ad ? 1 : 0;
        }
        float fia = (float)ia;
        #pragma unroll
        for (int msk = 1; msk < 16; msk <<= 1) {
            s   += __shfl_xor(s,   msk);
            a2  += __shfl_xor(a2,  msk);
            a3  += __shfl_xor(a3,  msk);
            fia += __shfl_xor(fia, msk);
        }
        if (c == 0) {
            float4 pk4; pk4.x = s; pk4.y = a2; pk4.z = a3; pk4.w = fia;
            *(float4*)&rowpart[baseR + g*4 + r][half * 4] = pk4;
        }
    }

    __syncthreads();   // rowpart complete; even-wave fpart8 write-back complete

    // combine halves: thread tid<128 owns one row
    if (tid < KK) {
        const float4 pa = *(const float4*)&rowpart[tid][0];
        const float4 pb = *(const float4*)&rowpart[tid][4];
        const float s   = pa.x + pb.x;
        const float a2  = pa.y + pb.y;
        const float a3  = pa.z + pb.z;
        const float fia = pa.w + pb.w;
        // sum (adj-p)^2 = sum(adj) - invS*(2 sum(adj e) - invS sum(e^2))
        const float invS = __builtin_amdgcn_rcpf(s);
        float sq = sqrtf(fmaxf(fia - invS * (2.f * a2 - invS * a3), 0.f));
        #pragma unroll
        for (int m = 1; m < 64; m <<= 1) sq += __shfl_xor(sq, m);
        if (lane == 0) spart[wave] = sq;   // wave 0 or 1
    }

    __syncthreads();

    if (wave == 0) {
        float4 d = make_float4(0.f, 0.f, 0.f, 0.f);
        #pragma unroll
        for (int j = 0; j < 8; ++j) {
            const float4 p = *(const float4*)&fpart8[j][4 * lane];
            d.x += p.x; d.y += p.y; d.z += p.z; d.w += p.w;
        }
        const float inv = 1.f / 128.f;
        d.x *= inv; d.y *= inv; d.z *= inv; d.w *= inv;
        float q2 = dot4(d, d);
        #pragma unroll
        for (int m = 1; m < 64; m <<= 1) q2 += __shfl_xor(q2, m);
        if (lane == 0)
            score_raw[b] = (spart[0] + spart[1]) * (1.f / 128.f) + sqrtf(q2);
    }
}

__global__ __launch_bounds__(1024) void finalize(
    const float* __restrict__ score_raw,
    const int*   __restrict__ label,
    float*       __restrict__ out)
{
    __shared__ float wmin[16], wmax[16], wsum[16];
    const int tid = threadIdx.x;
    const float s = score_raw[tid];
    float mn = s, mx = s;
    #pragma unroll
    for (int m = 1; m < 64; m <<= 1) {
        mn = fminf(mn, __shfl_xor(mn, m));
        mx = fmaxf(mx, __shfl_xor(mx, m));
    }
    if ((tid & 63) == 0) { wmin[tid >> 6] = mn; wmax[tid >> 6] = mx; }
    __syncthreads();
    float gmn = wmin[0], gmx = wmax[0];
    #pragma unroll
    for (int w = 1; w < 16; ++w) {
        gmn = fminf(gmn, wmin[w]);
        gmx = fmaxf(gmx, wmax[w]);
    }
    const float score = (s - gmn) / (gmx - gmn);
    out[tid] = score;

    const float y  = (float)label[tid];
    const float sc = fminf(fmaxf(score, 1e-7f), 1.f - 1e-7f);
    float term = -(y * logf(sc) + (1.f - y) * log1pf(-sc));
    #pragma unroll
    for (int m = 1; m < 64; m <<= 1) term += __shfl_xor(term, m);
    if ((tid & 63) == 0) wsum[tid >> 6] = term;
    __syncthreads();
    if (tid == 0) {
        float tot = 0.f;
        #pragma unroll
        for (int w = 0; w < 16; ++w) tot += wsum[w];
        out[BB] = tot / (1024.f * 1024.f);
    }
}

extern "C" void kernel_launch(void* const* d_in, const int* in_sizes, int n_in,
                              void* d_out, int out_size, void* d_ws, size_t ws_size,
                              hipStream_t stream) {
    const float* feature = (const float*)d_in[0];
    const float* text    = (const float*)d_in[1];
    const float* virt    = (const float*)d_in[2];
    const float* gumbel  = (const float*)d_in[3];
    const int*   ego     = (const int*)d_in[4];
    const int*   adj     = (const int*)d_in[5];
    const int*   label   = (const int*)d_in[6];
    float* out       = (float*)d_out;
    float* score_raw = (float*)d_ws;

    fused_main<<<BB, 1024, 0, stream>>>(feature, text, virt, gumbel, ego, adj, score_raw);
    finalize<<<1, 1024, 0, stream>>>(score_raw, label, out);
}